// Round 7
// baseline (367.492 us; speedup 1.0000x reference)
//
#include <hip/hip_runtime.h>
#include <math.h>
#include <limits.h>

#define QN 1024
#define NN 50000
#define NPAD 50048        /* 391*128 exactly */
#define DD 512
#define KNN 10
#define NT 128
#define QTB 128
#define BK 32
#define NS 391
#define QB 8
#define NSAMP 31
#define NREST (NS - NSAMP)    /* 360 = 8*45 -> XCD remap stays bijective */
#define CAP 512
#define SLACK 4.0f            /* hi-only d~ error: sigma~0.075 on d^2; 4.0 ~ 26 sigma */
#define LCAP 1152             /* >= NSAMP*KNN + CAP worst case (310+512) */

/* workspace layout, in 4-byte words */
#define WS_D2  0
#define WS_TAU 50048                       /* float[1024] (threshold, slacked) */
#define WS_CNT (WS_TAU + 1024)
#define WS_XH  (WS_CNT + 1024)
#define WS_CKS (WS_XH + QN * DD / 2)       /* u64[QN*NSAMP*KNN] */
#define WS_BUF (WS_CKS + QN * NSAMP * KNN * 2)
#define WS_DH  (WS_BUF + QN * CAP * 2)     /* tiled data hi: 391*16*8192 B */
#define WS_END (WS_DH + NS * 16 * 2048)

typedef __attribute__((ext_vector_type(8))) short short8;
typedef __attribute__((ext_vector_type(4))) float f32x4;
typedef unsigned long long u64;

__device__ __forceinline__ u64 mkkey(float f, int idx) {
  unsigned u = __float_as_uint(f);
  unsigned m = u ^ ((unsigned)((int)u >> 31) | 0x80000000u);
  return ((u64)m << 32) | (unsigned)idx;
}

/* decode the float from the hi-32 of a key */
__device__ __forceinline__ float keyhi_f(unsigned m) {
  unsigned u = (m & 0x80000000u) ? (m ^ 0x80000000u) : ~m;
  return __uint_as_float(u);
}

/* pack bf16(x),bf16(y) (round-to-nearest-even) into one u32 */
__device__ __forceinline__ unsigned cvth(float x, float y) {
  unsigned ux = __float_as_uint(x), uy = __float_as_uint(y);
  unsigned rx = ux + 0x7fffu + ((ux >> 16) & 1u);
  unsigned ry = uy + 0x7fffu + ((uy >> 16) & 1u);
  return (rx >> 16) | (ry & 0xffff0000u);
}

__device__ __forceinline__ void ins10(u64* kl, u64 k) {
#pragma unroll
  for (int u = 0; u < KNN; u++) {
    u64 lo = (k < kl[u]) ? k : kl[u];
    u64 hi = (k < kl[u]) ? kl[u] : k;
    kl[u] = lo; k = hi;
  }
}

/* ---- K0 (fused): blockIdx < NS -> data preconvert (hi) + row norms;
        blockIdx >= NS -> X preconvert (hi, frag-direct layout). --------- */
__global__ __launch_bounds__(256) void conv_kernel(
    const float* __restrict__ dat, const float* __restrict__ Xm,
    float* __restrict__ ws) {
  if ((int)blockIdx.x >= NS) {
    /* convx part: frag-direct hi image. 16B block index
       g = (b*16 + kc)*64 + l; b=row>>4, kc=col/32, l=sub*16+(row&15). */
    const int g = ((int)blockIdx.x - NS) * 256 + threadIdx.x;  /* 0..65535 */
    const int b = g >> 10, kc = (g >> 6) & 15, l = g & 63;
    const int row = b * 16 + (l & 15);
    const int col = kc * 32 + (l >> 4) * 8;
    const float4* p = (const float4*)(Xm + (size_t)row * DD + col);
    float4 v0 = p[0], v1 = p[1];
    ((uint4*)(ws + WS_XH))[g] = make_uint4(
        cvth(v0.x, v0.y), cvth(v0.z, v0.w), cvth(v1.x, v1.y), cvth(v1.z, v1.w));
    return;
  }
  const int slice = blockIdx.x;
  const int t = threadIdx.x;
  const int row = t >> 1, h2 = t & 1;
  const int gr = slice * NT + row;
  const int r15 = row & 15;
  float s = 0.f;
#pragma unroll
  for (int kc8 = 0; kc8 < 8; kc8++) {
    const int kc = h2 * 8 + kc8;
    float4 v[8];
    if (gr < NN) {
      const float4* src = (const float4*)(dat + (size_t)gr * DD + kc * 32);
#pragma unroll
      for (int j = 0; j < 8; j++) v[j] = src[j];
    } else {
#pragma unroll
      for (int j = 0; j < 8; j++) v[j] = make_float4(0.f, 0.f, 0.f, 0.f);
    }
    unsigned hw[16];
#pragma unroll
    for (int j = 0; j < 8; j++) {
      s = fmaf(v[j].x, v[j].x, s); s = fmaf(v[j].y, v[j].y, s);
      s = fmaf(v[j].z, v[j].z, s); s = fmaf(v[j].w, v[j].w, s);
      hw[2 * j]     = cvth(v[j].x, v[j].y);
      hw[2 * j + 1] = cvth(v[j].z, v[j].w);
    }
    uint4* dhp = (uint4*)((unsigned char*)(ws + WS_DH) +
                          (((size_t)slice * 16 + kc) * 8 + (row >> 4)) * 1024);
#pragma unroll
    for (int qd = 0; qd < 4; qd++)
      dhp[qd * 16 + r15] = make_uint4(hw[4 * qd], hw[4 * qd + 1], hw[4 * qd + 2], hw[4 * qd + 3]);
  }
  s += __shfl_xor(s, 1, 64);
  if (h2 == 0) ws[WS_D2 + gr] = (gr < NN) ? s : __builtin_inff();
}

/* ------- K2: hi-only GEMM filter core (NT=128, 256 thr).
   MODE 0 = sampled per-slice top-10 of approx d~ (feeds tau);
   MODE 1 = threshold filter (d~ < tau+SLACK -> survivor buf).
   r5/r6 lesson: the K-loop was latency-bound on cross-wave LDS
   dependencies (each __syncthreads forces a vmcnt(0) drain; hand-rolled
   raw-barrier pipelining made it WORSE by defeating compiler
   scheduling). This version removes LDS from the K-loop entirely:
   BOTH A and B images are frag-direct, so each wave reads its 8
   fragments straight from global (L2-resident, XCD-clustered) into
   registers, 2-deep software pipeline, zero barriers, zero inline-asm.
   Per-wave counted vmcnt is inserted by the compiler. ----------------- */
struct StageT { unsigned char bh[8192]; };
struct EpiT  { float sq[64][132]; };
struct ListT { u64 kl[64][4][KNN]; };

template <int PRE, int MODE> struct Smem;
template <> struct Smem<1, 0> { union { EpiT e; ListT l; }; };
template <> struct Smem<1, 1> { float tau[128]; };
template <> struct Smem<0, 0> { union { StageT s; EpiT e; ListT l; }; };
template <> struct Smem<0, 1> { StageT s; float tau[128]; };

/* r2 lesson: min-waves>=4 caps VGPR too low and spills the accumulator.
   Keep (256,3). */
template <int PRE, int MODE>
__global__ __launch_bounds__(256, 3) void knn_chunk(
    const float* __restrict__ dat, float* __restrict__ ws, int soff) {
  __shared__ __align__(16) Smem<PRE, MODE> sm;
  /* XCD-aware remap (MODE 1): cluster a slice's 8 qblocks onto one XCD
     (r3-verified: FETCH 374->58 MB). Bijective for gridDim.y % 8 == 0. */
  int bqx, bsy;
  if (MODE == 1 && (gridDim.y & 7) == 0) {
    const int n = (int)(blockIdx.y * gridDim.x + blockIdx.x);
    const int m = n >> 3;
    const int ypx = (int)(gridDim.y >> 3);
    bqx = m & 7;
    bsy = (n & 7) * ypx + (m >> 3);
  } else {
    bqx = blockIdx.x; bsy = blockIdx.y;
  }
  const int qbase = bqx * QTB;
  const int slice = bsy + soff;
  const int nbase = slice * NT;
  const int t = threadIdx.x;
  const int lane = t & 63, wave = t >> 6;
  const int wn = wave & 1, wq = wave >> 1;
  const unsigned char* dh = (const unsigned char*)(ws + WS_DH);
  const char* xfh = (const char*)(ws + WS_XH);
  /* A-frag byte base: block ((bqx*8 + wq*4 + i)*16 + kc)*64 + lane */
  const int abase = (((bqx * 8 + wq * 4) * 16) * 64 + lane) * 16;
  /* B-frag byte base: ((slice*16 + kc)*8 + wn*4 + i)*1024 + lane*16 */
  const unsigned char* bbase = dh + ((size_t)slice * 16 * 8 + wn * 4) * 1024 + lane * 16;

  f32x4 acc[4][4];
#pragma unroll
  for (int i = 0; i < 4; i++)
#pragma unroll
    for (int j = 0; j < 4; j++) acc[i][j] = (f32x4)0.f;

  if constexpr (PRE == 1) {
    /* barrier-free register pipeline: issue loads for kc+1, MFMA on kc */
    short8 ca[4], cb[4];
#pragma unroll
    for (int i = 0; i < 4; i++) {
      ca[i] = *(const short8*)(xfh + abase + i * 16384);
      cb[i] = *(const short8*)(bbase + i * 1024);
    }
#pragma unroll
    for (int kc = 0; kc < 16; kc++) {
      short8 na[4], nb[4];
      if (kc < 15) {
#pragma unroll
        for (int i = 0; i < 4; i++) {
          na[i] = *(const short8*)(xfh + abase + i * 16384 + (kc + 1) * 1024);
          nb[i] = *(const short8*)(bbase + ((kc + 1) * 8 + i) * 1024);
        }
      }
#pragma unroll
      for (int mt = 0; mt < 4; mt++)
#pragma unroll
        for (int nt = 0; nt < 4; nt++)
          acc[mt][nt] = __builtin_amdgcn_mfma_f32_16x16x32_bf16(ca[mt], cb[nt], acc[mt][nt], 0, 0, 0);
      if (kc < 15) {
#pragma unroll
        for (int i = 0; i < 4; i++) { ca[i] = na[i]; cb[i] = nb[i]; }
      }
    }
  } else {
    /* fallback: in-loop B hi-conversion staged through LDS (r5-proven) */
    const int brow = t >> 1, bh_half = t & 1;
    const int bgr = nbase + brow;
    const int bpanel = (brow >> 4) * 1024;
    const int bchunk = (brow & 15) * 16;
    for (int kc = 0; kc < 16; kc++) {
      const int kk = kc * BK;
      short8 fah[4];
#pragma unroll
      for (int i = 0; i < 4; i++)
        fah[i] = *(const short8*)(xfh + abase + i * 16384 + kc * 1024);
      __syncthreads();
      {
        float4 v0 = make_float4(0.f, 0.f, 0.f, 0.f), v1 = v0, v2 = v0, v3 = v0;
        if (bgr < NN) {
          const float4* src = (const float4*)(dat + (size_t)bgr * DD + kk + bh_half * 16);
          v0 = src[0]; v1 = src[1]; v2 = src[2]; v3 = src[3];
        }
        unsigned char* bhp = sm.s.bh + bpanel;
        *(uint4*)(bhp + (2 * bh_half) * 256 + bchunk) =
            make_uint4(cvth(v0.x, v0.y), cvth(v0.z, v0.w), cvth(v1.x, v1.y), cvth(v1.z, v1.w));
        *(uint4*)(bhp + (2 * bh_half + 1) * 256 + bchunk) =
            make_uint4(cvth(v2.x, v2.y), cvth(v2.z, v2.w), cvth(v3.x, v3.y), cvth(v3.z, v3.w));
      }
      __syncthreads();
      const int fragoff = lane * 16;
      short8 fbh[4];
#pragma unroll
      for (int i = 0; i < 4; i++)
        fbh[i] = *(const short8*)(sm.s.bh + (wn * 4 + i) * 1024 + fragoff);
      __syncthreads();
#pragma unroll
      for (int mt = 0; mt < 4; mt++)
#pragma unroll
        for (int nt = 0; nt < 4; nt++)
          acc[mt][nt] = __builtin_amdgcn_mfma_f32_16x16x32_bf16(fah[mt], fbh[nt], acc[mt][nt], 0, 0, 0);
    }
  }

  if constexpr (MODE == 0) {
#pragma unroll
    for (int pass = 0; pass < 2; pass++) {
      __syncthreads();
      if (wq == pass) {
#pragma unroll
        for (int nt = 0; nt < 4; nt++) {
          int col = wn * 64 + nt * 16 + (lane & 15);
          float d2v = ws[WS_D2 + nbase + col];
#pragma unroll
          for (int mt = 0; mt < 4; mt++)
#pragma unroll
            for (int rg = 0; rg < 4; rg++) {
              int lr = mt * 16 + (lane >> 4) * 4 + rg;
              sm.e.sq[lr][col] = fmaf(-2.f, acc[mt][nt][rg], d2v);
            }
        }
      }
      __syncthreads();
      {
        const int r = t >> 2, s = t & 3;
        u64 kl[KNN];
#pragma unroll
        for (int u = 0; u < KNN; u++) kl[u] = ~0ull;
        for (int jj = 0; jj < 32; jj++) {
          int c = s * 32 + ((jj + r + 8 * s) & 31);
          float v = sm.e.sq[r][c];
          ins10(kl, mkkey(v, nbase + c));
        }
        __syncthreads();
#pragma unroll
        for (int u = 0; u < KNN; u++) sm.l.kl[r][s][u] = kl[u];
      }
      __syncthreads();
      if (t < 64) {
        u64* dst = ((u64*)(ws + WS_CKS)) +
                   ((size_t)(qbase + pass * 64 + t) * NSAMP + blockIdx.y) * KNN;
        int h0 = 0, h1 = 0, h2 = 0, h3 = 0;
        for (int pick = 0; pick < KNN; pick++) {
          u64 k0 = sm.l.kl[t][0][h0], k1 = sm.l.kl[t][1][h1];
          u64 k2 = sm.l.kl[t][2][h2], k3 = sm.l.kl[t][3][h3];
          u64 best = k0; int bm = 0;
          if (k1 < best) { best = k1; bm = 1; }
          if (k2 < best) { best = k2; bm = 2; }
          if (k3 < best) { best = k3; bm = 3; }
          dst[pick] = best;
          h0 += (bm == 0); h1 += (bm == 1); h2 += (bm == 2); h3 += (bm == 3);
        }
      }
    }
  } else {
    /* threshold filter: float compare against slacked tau */
    if (t < 128) sm.tau[t] = ws[WS_TAU + qbase + t];
    __syncthreads();
    unsigned* cnt = (unsigned*)(ws + WS_CNT);
    u64* buf = (u64*)(ws + WS_BUF);
    float d2v[4];
#pragma unroll
    for (int nt = 0; nt < 4; nt++)
      d2v[nt] = ws[WS_D2 + nbase + wn * 64 + nt * 16 + (lane & 15)];
#pragma unroll
    for (int mt = 0; mt < 4; mt++)
#pragma unroll
      for (int rg = 0; rg < 4; rg++) {
        int row = wq * 64 + mt * 16 + (lane >> 4) * 4 + rg;
        float tr = sm.tau[row];
#pragma unroll
        for (int nt = 0; nt < 4; nt++) {
          float d = fmaf(-2.f, acc[mt][nt][rg], d2v[nt]);
          if (d < tr) {
            int col = nbase + wn * 64 + nt * 16 + (lane & 15);
            int q = qbase + row;
            unsigned slot = atomicAdd(cnt + q, 1u);
            if (slot < CAP) buf[(size_t)q * CAP + slot] = mkkey(d, col);
          }
        }
      }
  }
}

/* ---------------- K2t: per-query tau = 10th of sampled keys + SLACK ---- */
__global__ __launch_bounds__(64) void tau_kernel(float* __restrict__ ws) {
  const int q = blockIdx.x;
  const int t = threadIdx.x;
  const u64* samp = ((const u64*)(ws + WS_CKS)) + (size_t)q * NSAMP * KNN;
  const int NC = NSAMP * KNN;
  u64 kl[KNN];
#pragma unroll
  for (int u = 0; u < KNN; u++) kl[u] = ~0ull;
  for (int j = t; j < NC; j += 64) ins10(kl, samp[j]);
  __shared__ u64 wk[64][KNN];
  __shared__ u64 m2[8][KNN];
#pragma unroll
  for (int u = 0; u < KNN; u++) wk[t][u] = kl[u];
  __syncthreads();
  if (t < 8) {
    int h[8] = {0, 0, 0, 0, 0, 0, 0, 0};
    for (int pick = 0; pick < KNN; pick++) {
      u64 best = ~0ull; int bm = 0;
#pragma unroll
      for (int m = 0; m < 8; m++) {
        u64 km = wk[t * 8 + m][h[m]];
        if (km < best) { best = km; bm = m; }
      }
      m2[t][pick] = best;
#pragma unroll
      for (int m = 0; m < 8; m++) h[m] += (bm == m);
    }
  }
  __syncthreads();
  if (t == 0) {
    int h[8] = {0, 0, 0, 0, 0, 0, 0, 0};
    u64 best = 0;
    for (int pick = 0; pick < KNN; pick++) {
      best = ~0ull; int bm = 0;
#pragma unroll
      for (int m = 0; m < 8; m++) {
        u64 km = m2[m][h[m]];
        if (km < best) { best = km; bm = m; }
      }
#pragma unroll
      for (int m = 0; m < 8; m++) h[m] += (bm == m);
    }
    ws[WS_TAU + q] = keyhi_f((unsigned)(best >> 32)) + SLACK;
    ((unsigned*)(ws + WS_CNT))[q] = 0u;
  }
}

/* ---------------- K3: candidate gather + exact fp32 refine + mode ------ */
__global__ __launch_bounds__(256) void knn_final(
    const int* __restrict__ targets, const float* __restrict__ Xm,
    const float* __restrict__ dat, float* __restrict__ ws,
    float* __restrict__ out) {
  const int q = blockIdx.x;
  const int t = threadIdx.x;
  const int lane = t & 63, wave = t >> 6;
  __shared__ float qrow[DD];
  __shared__ unsigned lst[LCAP];
  __shared__ int nlist;
  __shared__ u64 wk4[4][KNN];
  if (t == 0) nlist = 0;
  if (t < 128) ((float4*)qrow)[t] = ((const float4*)(Xm + (size_t)q * DD))[t];
  __syncthreads();
  const float tr = ws[WS_TAU + q];
  const u64* samp = ((const u64*)(ws + WS_CKS)) + (size_t)q * NSAMP * KNN;
  for (int j = t; j < NSAMP * KNN; j += 256) {
    u64 k = samp[j];
    if (keyhi_f((unsigned)(k >> 32)) < tr) {
      int s_ = atomicAdd(&nlist, 1);
      if (s_ < LCAP) lst[s_] = (unsigned)k;
    }
  }
  unsigned c = ((const unsigned*)(ws + WS_CNT))[q];
  if (c > CAP) c = CAP;
  const u64* buf = ((const u64*)(ws + WS_BUF)) + (size_t)q * CAP;
  for (int j = t; j < (int)c; j += 256) {
    int s_ = atomicAdd(&nlist, 1);
    if (s_ < LCAP) lst[s_] = (unsigned)buf[j];
  }
  __syncthreads();
  const int n = nlist < LCAP ? nlist : LCAP;

  u64 kl[KNN];
#pragma unroll
  for (int u = 0; u < KNN; u++) kl[u] = ~0ull;
  const float4* qv = (const float4*)qrow;
  const float4 q0 = qv[lane * 2], q1 = qv[lane * 2 + 1];
  /* 2-way ILP: two candidates per iteration so the serial shfl-reduce
     chains overlap; early-reject guard before ins10. */
  for (int j = wave; j < n; j += 8) {
    const unsigned i0 = lst[j];
    const int has1 = (j + 4) < n;
    const unsigned i1 = has1 ? lst[j + 4] : i0;
    const float4* x0 = (const float4*)(dat + (size_t)i0 * DD) + lane * 2;
    const float4* x1 = (const float4*)(dat + (size_t)i1 * DD) + lane * 2;
    const float4 a0 = x0[0], a1 = x0[1];
    const float4 b0 = x1[0], b1 = x1[1];
    float p0 = a0.x * q0.x, p1 = b0.x * q0.x;
    p0 = fmaf(a0.y, q0.y, p0); p1 = fmaf(b0.y, q0.y, p1);
    p0 = fmaf(a0.z, q0.z, p0); p1 = fmaf(b0.z, q0.z, p1);
    p0 = fmaf(a0.w, q0.w, p0); p1 = fmaf(b0.w, q0.w, p1);
    p0 = fmaf(a1.x, q1.x, p0); p1 = fmaf(b1.x, q1.x, p1);
    p0 = fmaf(a1.y, q1.y, p0); p1 = fmaf(b1.y, q1.y, p1);
    p0 = fmaf(a1.z, q1.z, p0); p1 = fmaf(b1.z, q1.z, p1);
    p0 = fmaf(a1.w, q1.w, p0); p1 = fmaf(b1.w, q1.w, p1);
#pragma unroll
    for (int s_ = 1; s_ < 64; s_ <<= 1) {
      p0 += __shfl_xor(p0, s_, 64);
      p1 += __shfl_xor(p1, s_, 64);
    }
    float d0 = fmaf(-2.f, p0, ws[WS_D2 + i0]);
    u64 k0 = mkkey(d0, (int)i0);
    if (k0 < kl[KNN - 1]) ins10(kl, k0);
    if (has1) {
      float d1 = fmaf(-2.f, p1, ws[WS_D2 + i1]);
      u64 k1 = mkkey(d1, (int)i1);
      if (k1 < kl[KNN - 1]) ins10(kl, k1);
    }
  }
  if (lane == 0)
#pragma unroll
    for (int u = 0; u < KNN; u++) wk4[wave][u] = kl[u];
  __syncthreads();
  if (t == 0) {
    int h[4] = {0, 0, 0, 0};
    int fi[KNN];
    for (int pick = 0; pick < KNN; pick++) {
      u64 best = ~0ull; int bm = 0;
#pragma unroll
      for (int m = 0; m < 4; m++) {
        u64 km = wk4[m][h[m]];
        if (km < best) { best = km; bm = m; }
      }
      fi[pick] = (int)(unsigned)(best & 0xffffffffu);
      h[bm]++;
    }
    int lab[KNN];
#pragma unroll
    for (int u = 0; u < KNN; u++) lab[u] = targets[fi[u]];
    int bc = 0, bl = INT_MAX;
#pragma unroll
    for (int i = 0; i < KNN; i++) {
      int cc = 0;
#pragma unroll
      for (int j = 0; j < KNN; j++) cc += (lab[j] == lab[i]) ? 1 : 0;
      if (cc > bc || (cc == bc && lab[i] < bl)) { bc = cc; bl = lab[i]; }
    }
    out[q] = (float)bl;
  }
}

extern "C" void kernel_launch(void* const* d_in, const int* in_sizes, int n_in,
                              void* d_out, int out_size, void* d_ws, size_t ws_size,
                              hipStream_t stream) {
  const float* Xm  = (const float*)d_in[0];
  const float* dat = (const float*)d_in[1];
  const int* targets = (const int*)d_in[2];
  float* out = (float*)d_out;
  float* ws  = (float*)d_ws;
  const bool pre = ws_size >= (size_t)WS_END * 4;   /* constant per process */

  hipLaunchKernelGGL(conv_kernel, dim3(NS + QN * DD / 8 / 256), dim3(256), 0,
                     stream, dat, Xm, ws);
  if (pre) {
    hipLaunchKernelGGL((knn_chunk<1, 0>), dim3(QB, NSAMP), dim3(256), 0, stream, dat, ws, 0);
    hipLaunchKernelGGL(tau_kernel, dim3(QN), dim3(64), 0, stream, ws);
    hipLaunchKernelGGL((knn_chunk<1, 1>), dim3(QB, NREST), dim3(256), 0, stream, dat, ws, NSAMP);
  } else {
    hipLaunchKernelGGL((knn_chunk<0, 0>), dim3(QB, NSAMP), dim3(256), 0, stream, dat, ws, 0);
    hipLaunchKernelGGL(tau_kernel, dim3(QN), dim3(64), 0, stream, ws);
    hipLaunchKernelGGL((knn_chunk<0, 1>), dim3(QB, NREST), dim3(256), 0, stream, dat, ws, NSAMP);
  }
  hipLaunchKernelGGL(knn_final, dim3(QN), dim3(256), 0, stream, targets, Xm, dat, ws, out);
}

// Round 8
// 335.214 us; speedup vs baseline: 1.0963x; 1.0963x over previous
//
#include <hip/hip_runtime.h>
#include <math.h>
#include <limits.h>

#define QN 1024
#define NN 50000
#define NPAD 50048        /* 391*128 exactly */
#define DD 512
#define KNN 10
#define NT 128
#define QTB 128
#define BK 32
#define NS 391
#define QB 8
#define NSAMP 31
#define NREST (NS - NSAMP)    /* 360 = 8*45 -> XCD remap stays bijective */
#define CAP 512
#define SLACK 4.0f            /* hi-only d~ error: sigma~0.075 on d^2; 4.0 ~ 26 sigma */
#define LCAP 1152             /* >= NSAMP*KNN + CAP worst case (310+512) */

/* workspace layout, in 4-byte words */
#define WS_D2  0
#define WS_TAU 50048                       /* float[1024] (threshold, slacked) */
#define WS_CNT (WS_TAU + 1024)
#define WS_XH  (WS_CNT + 1024)
#define WS_CKS (WS_XH + QN * DD / 2)       /* u64[QN*NSAMP*KNN] */
#define WS_BUF (WS_CKS + QN * NSAMP * KNN * 2)
#define WS_DH  (WS_BUF + QN * CAP * 2)     /* tiled data hi: 391*16*8192 B */
#define WS_END (WS_DH + NS * 16 * 2048)

typedef __attribute__((ext_vector_type(8))) short short8;
typedef __attribute__((ext_vector_type(4))) float f32x4;
typedef unsigned long long u64;

__device__ __forceinline__ u64 mkkey(float f, int idx) {
  unsigned u = __float_as_uint(f);
  unsigned m = u ^ ((unsigned)((int)u >> 31) | 0x80000000u);
  return ((u64)m << 32) | (unsigned)idx;
}

/* decode the float from the hi-32 of a key */
__device__ __forceinline__ float keyhi_f(unsigned m) {
  unsigned u = (m & 0x80000000u) ? (m ^ 0x80000000u) : ~m;
  return __uint_as_float(u);
}

/* pack bf16(x),bf16(y) (round-to-nearest-even) into one u32 */
__device__ __forceinline__ unsigned cvth(float x, float y) {
  unsigned ux = __float_as_uint(x), uy = __float_as_uint(y);
  unsigned rx = ux + 0x7fffu + ((ux >> 16) & 1u);
  unsigned ry = uy + 0x7fffu + ((uy >> 16) & 1u);
  return (rx >> 16) | (ry & 0xffff0000u);
}

__device__ __forceinline__ void glds16(const void* g, void* l) {
  __builtin_amdgcn_global_load_lds(
      (const __attribute__((address_space(1))) unsigned*)g,
      (__attribute__((address_space(3))) unsigned*)l, 16, 0, 0);
}

__device__ __forceinline__ void ins10(u64* kl, u64 k) {
#pragma unroll
  for (int u = 0; u < KNN; u++) {
    u64 lo = (k < kl[u]) ? k : kl[u];
    u64 hi = (k < kl[u]) ? kl[u] : k;
    kl[u] = lo; k = hi;
  }
}

/* ---- K0 (fused): blockIdx < NS -> data preconvert (hi) + row norms;
        blockIdx >= NS -> X preconvert (hi, frag-direct layout). --------- */
__global__ __launch_bounds__(256) void conv_kernel(
    const float* __restrict__ dat, const float* __restrict__ Xm,
    float* __restrict__ ws) {
  if ((int)blockIdx.x >= NS) {
    /* convx part: frag-direct hi image. 16B block index
       g = (b*16 + kc)*64 + l; b=row>>4, kc=col/32, l=sub*16+(row&15). */
    const int g = ((int)blockIdx.x - NS) * 256 + threadIdx.x;  /* 0..65535 */
    const int b = g >> 10, kc = (g >> 6) & 15, l = g & 63;
    const int row = b * 16 + (l & 15);
    const int col = kc * 32 + (l >> 4) * 8;
    const float4* p = (const float4*)(Xm + (size_t)row * DD + col);
    float4 v0 = p[0], v1 = p[1];
    ((uint4*)(ws + WS_XH))[g] = make_uint4(
        cvth(v0.x, v0.y), cvth(v0.z, v0.w), cvth(v1.x, v1.y), cvth(v1.z, v1.w));
    return;
  }
  const int slice = blockIdx.x;
  const int t = threadIdx.x;
  const int row = t >> 1, h2 = t & 1;
  const int gr = slice * NT + row;
  const int r15 = row & 15;
  float s = 0.f;
#pragma unroll
  for (int kc8 = 0; kc8 < 8; kc8++) {
    const int kc = h2 * 8 + kc8;
    float4 v[8];
    if (gr < NN) {
      const float4* src = (const float4*)(dat + (size_t)gr * DD + kc * 32);
#pragma unroll
      for (int j = 0; j < 8; j++) v[j] = src[j];
    } else {
#pragma unroll
      for (int j = 0; j < 8; j++) v[j] = make_float4(0.f, 0.f, 0.f, 0.f);
    }
    unsigned hw[16];
#pragma unroll
    for (int j = 0; j < 8; j++) {
      s = fmaf(v[j].x, v[j].x, s); s = fmaf(v[j].y, v[j].y, s);
      s = fmaf(v[j].z, v[j].z, s); s = fmaf(v[j].w, v[j].w, s);
      hw[2 * j]     = cvth(v[j].x, v[j].y);
      hw[2 * j + 1] = cvth(v[j].z, v[j].w);
    }
    uint4* dhp = (uint4*)((unsigned char*)(ws + WS_DH) +
                          (((size_t)slice * 16 + kc) * 8 + (row >> 4)) * 1024);
#pragma unroll
    for (int qd = 0; qd < 4; qd++)
      dhp[qd * 16 + r15] = make_uint4(hw[4 * qd], hw[4 * qd + 1], hw[4 * qd + 2], hw[4 * qd + 3]);
  }
  s += __shfl_xor(s, 1, 64);
  if (h2 == 0) ws[WS_D2 + gr] = (gr < NN) ? s : __builtin_inff();
}

/* ------- K2: hi-only GEMM filter core (NT=128, 256 thr).
   MODE 0 = sampled per-slice top-10 of approx d~ (feeds tau);
   MODE 1 = threshold filter (d~ < tau+SLACK -> survivor buf).
   r4/r5/r7 calibration: kernel is L2-BW-bound at ~25 B/cyc/CU; wall time
   tracks L2 bytes (r5: 24 KB/block-kc = 973 cyc measured = 72KB/25 for 3
   resident blocks). This version stages BOTH A and B through LDS via
   global_load_lds (kills the wq-pair A duplication): 16 KB/block-kc.
   Schedule = r5's proven two-barrier shape, byte-for-byte. ------------- */
struct StageT { unsigned char ah[8192], bh[8192]; };
struct EpiT  { float sq[64][132]; };
struct ListT { u64 kl[64][4][KNN]; };

template <int MODE> struct SmemSel {
  union U { StageT s; EpiT e; ListT l; };   /* MODE 0: 33792 B */
};
template <> struct SmemSel<1> {
  struct U { StageT s; float tau[128]; };   /* MODE 1: 16896 B */
};

/* r2 lesson: min-waves>=4 caps VGPR too low and spills the accumulator.
   Keep (256,3). */
template <int PRE, int MODE>
__global__ __launch_bounds__(256, 3) void knn_chunk(
    const float* __restrict__ dat, float* __restrict__ ws, int soff) {
  __shared__ __align__(16) typename SmemSel<MODE>::U sm;
  /* XCD-aware remap (MODE 1): cluster a slice's 8 qblocks onto one XCD
     (r3-verified: FETCH 374->58 MB). Bijective for gridDim.y % 8 == 0. */
  int bqx, bsy;
  if (MODE == 1 && (gridDim.y & 7) == 0) {
    const int n = (int)(blockIdx.y * gridDim.x + blockIdx.x);
    const int m = n >> 3;
    const int ypx = (int)(gridDim.y >> 3);
    bqx = m & 7;
    bsy = (n & 7) * ypx + (m >> 3);
  } else {
    bqx = blockIdx.x; bsy = blockIdx.y;
  }
  const int qbase = bqx * QTB;
  const int slice = bsy + soff;
  const int nbase = slice * NT;
  const int t = threadIdx.x;
  const int lane = t & 63, wave = t >> 6;
  const int wn = wave & 1, wq = wave >> 1;
  const unsigned char* dh = (const unsigned char*)(ws + WS_DH);
  const char* xfh = (const char*)(ws + WS_XH);

  f32x4 acc[4][4];
#pragma unroll
  for (int i = 0; i < 4; i++)
#pragma unroll
    for (int j = 0; j < 4; j++) acc[i][j] = (f32x4)0.f;

  /* stage(kc): 4 DMA loads per wave: A panels {wave*2, wave*2+1} and
     B panels {wave*2, wave*2+1}. LDS content byte-identical to the
     frag-direct images. */
  auto stage = [&](int kc) {
#pragma unroll
    for (int i = 0; i < 2; i++) {
      int pp = wave * 2 + i;
      const char* ga = xfh +
          ((((size_t)(bqx * 8 + pp) * 16 + kc) * 64) + lane) * 16;
      glds16(ga, sm.s.ah + pp * 1024);
    }
#pragma unroll
    for (int i = 0; i < 2; i++) {
      int p = wave * 2 + i;
      const unsigned char* gb = dh +
          (((size_t)slice * 16 + kc) * 8 + p) * 1024 + lane * 16;
      glds16(gb, sm.s.bh + p * 1024);
    }
  };

  if (PRE) {
    stage(0);
    for (int kc = 0; kc < 16; kc++) {
      __syncthreads();                    /* DMA(kc) complete */
      const int fragoff = lane * 16;
      short8 fah[4], fbh[4];
#pragma unroll
      for (int i = 0; i < 4; i++) {
        fah[i] = *(const short8*)(sm.s.ah + (wq * 4 + i) * 1024 + fragoff);
        fbh[i] = *(const short8*)(sm.s.bh + (wn * 4 + i) * 1024 + fragoff);
      }
      __syncthreads();                    /* all waves done reading LDS */
      if (kc < 15) stage(kc + 1);         /* overlaps the MFMAs below */
#pragma unroll
      for (int mt = 0; mt < 4; mt++)
#pragma unroll
        for (int nt = 0; nt < 4; nt++)
          acc[mt][nt] = __builtin_amdgcn_mfma_f32_16x16x32_bf16(fah[mt], fbh[nt], acc[mt][nt], 0, 0, 0);
    }
  } else {
    /* fallback: A frag-direct from L2, in-loop B hi-conversion via LDS */
    const int abase = (((bqx * 8 + wq * 4) * 16) * 64 + lane) * 16;
    const int brow = t >> 1, bh_half = t & 1;
    const int bgr = nbase + brow;
    const int bpanel = (brow >> 4) * 1024;
    const int bchunk = (brow & 15) * 16;
    for (int kc = 0; kc < 16; kc++) {
      const int kk = kc * BK;
      short8 fah[4];
#pragma unroll
      for (int i = 0; i < 4; i++)
        fah[i] = *(const short8*)(xfh + abase + i * 16384 + kc * 1024);
      __syncthreads();
      {
        float4 v0 = make_float4(0.f, 0.f, 0.f, 0.f), v1 = v0, v2 = v0, v3 = v0;
        if (bgr < NN) {
          const float4* src = (const float4*)(dat + (size_t)bgr * DD + kk + bh_half * 16);
          v0 = src[0]; v1 = src[1]; v2 = src[2]; v3 = src[3];
        }
        unsigned char* bhp = sm.s.bh + bpanel;
        *(uint4*)(bhp + (2 * bh_half) * 256 + bchunk) =
            make_uint4(cvth(v0.x, v0.y), cvth(v0.z, v0.w), cvth(v1.x, v1.y), cvth(v1.z, v1.w));
        *(uint4*)(bhp + (2 * bh_half + 1) * 256 + bchunk) =
            make_uint4(cvth(v2.x, v2.y), cvth(v2.z, v2.w), cvth(v3.x, v3.y), cvth(v3.z, v3.w));
      }
      __syncthreads();
      const int fragoff = lane * 16;
      short8 fbh[4];
#pragma unroll
      for (int i = 0; i < 4; i++)
        fbh[i] = *(const short8*)(sm.s.bh + (wn * 4 + i) * 1024 + fragoff);
      __syncthreads();
#pragma unroll
      for (int mt = 0; mt < 4; mt++)
#pragma unroll
        for (int nt = 0; nt < 4; nt++)
          acc[mt][nt] = __builtin_amdgcn_mfma_f32_16x16x32_bf16(fah[mt], fbh[nt], acc[mt][nt], 0, 0, 0);
    }
  }

  if constexpr (MODE == 0) {
#pragma unroll
    for (int pass = 0; pass < 2; pass++) {
      __syncthreads();
      if (wq == pass) {
#pragma unroll
        for (int nt = 0; nt < 4; nt++) {
          int col = wn * 64 + nt * 16 + (lane & 15);
          float d2v = ws[WS_D2 + nbase + col];
#pragma unroll
          for (int mt = 0; mt < 4; mt++)
#pragma unroll
            for (int rg = 0; rg < 4; rg++) {
              int lr = mt * 16 + (lane >> 4) * 4 + rg;
              sm.e.sq[lr][col] = fmaf(-2.f, acc[mt][nt][rg], d2v);
            }
        }
      }
      __syncthreads();
      {
        const int r = t >> 2, s = t & 3;
        u64 kl[KNN];
#pragma unroll
        for (int u = 0; u < KNN; u++) kl[u] = ~0ull;
        for (int jj = 0; jj < 32; jj++) {
          int c = s * 32 + ((jj + r + 8 * s) & 31);
          float v = sm.e.sq[r][c];
          ins10(kl, mkkey(v, nbase + c));
        }
        __syncthreads();
#pragma unroll
        for (int u = 0; u < KNN; u++) sm.l.kl[r][s][u] = kl[u];
      }
      __syncthreads();
      if (t < 64) {
        u64* dst = ((u64*)(ws + WS_CKS)) +
                   ((size_t)(qbase + pass * 64 + t) * NSAMP + blockIdx.y) * KNN;
        int h0 = 0, h1 = 0, h2 = 0, h3 = 0;
        for (int pick = 0; pick < KNN; pick++) {
          u64 k0 = sm.l.kl[t][0][h0], k1 = sm.l.kl[t][1][h1];
          u64 k2 = sm.l.kl[t][2][h2], k3 = sm.l.kl[t][3][h3];
          u64 best = k0; int bm = 0;
          if (k1 < best) { best = k1; bm = 1; }
          if (k2 < best) { best = k2; bm = 2; }
          if (k3 < best) { best = k3; bm = 3; }
          dst[pick] = best;
          h0 += (bm == 0); h1 += (bm == 1); h2 += (bm == 2); h3 += (bm == 3);
        }
      }
    }
  } else {
    /* threshold filter: float compare against slacked tau */
    if (t < 128) sm.tau[t] = ws[WS_TAU + qbase + t];
    __syncthreads();
    unsigned* cnt = (unsigned*)(ws + WS_CNT);
    u64* buf = (u64*)(ws + WS_BUF);
    float d2v[4];
#pragma unroll
    for (int nt = 0; nt < 4; nt++)
      d2v[nt] = ws[WS_D2 + nbase + wn * 64 + nt * 16 + (lane & 15)];
#pragma unroll
    for (int mt = 0; mt < 4; mt++)
#pragma unroll
      for (int rg = 0; rg < 4; rg++) {
        int row = wq * 64 + mt * 16 + (lane >> 4) * 4 + rg;
        float tr = sm.tau[row];
#pragma unroll
        for (int nt = 0; nt < 4; nt++) {
          float d = fmaf(-2.f, acc[mt][nt][rg], d2v[nt]);
          if (d < tr) {
            int col = nbase + wn * 64 + nt * 16 + (lane & 15);
            int q = qbase + row;
            unsigned slot = atomicAdd(cnt + q, 1u);
            if (slot < CAP) buf[(size_t)q * CAP + slot] = mkkey(d, col);
          }
        }
      }
  }
}

/* ---------------- K2t: per-query tau = 10th of sampled keys + SLACK ---- */
__global__ __launch_bounds__(64) void tau_kernel(float* __restrict__ ws) {
  const int q = blockIdx.x;
  const int t = threadIdx.x;
  const u64* samp = ((const u64*)(ws + WS_CKS)) + (size_t)q * NSAMP * KNN;
  const int NC = NSAMP * KNN;
  u64 kl[KNN];
#pragma unroll
  for (int u = 0; u < KNN; u++) kl[u] = ~0ull;
  for (int j = t; j < NC; j += 64) ins10(kl, samp[j]);
  __shared__ u64 wk[64][KNN];
  __shared__ u64 m2[8][KNN];
#pragma unroll
  for (int u = 0; u < KNN; u++) wk[t][u] = kl[u];
  __syncthreads();
  if (t < 8) {
    int h[8] = {0, 0, 0, 0, 0, 0, 0, 0};
    for (int pick = 0; pick < KNN; pick++) {
      u64 best = ~0ull; int bm = 0;
#pragma unroll
      for (int m = 0; m < 8; m++) {
        u64 km = wk[t * 8 + m][h[m]];
        if (km < best) { best = km; bm = m; }
      }
      m2[t][pick] = best;
#pragma unroll
      for (int m = 0; m < 8; m++) h[m] += (bm == m);
    }
  }
  __syncthreads();
  if (t == 0) {
    int h[8] = {0, 0, 0, 0, 0, 0, 0, 0};
    u64 best = 0;
    for (int pick = 0; pick < KNN; pick++) {
      best = ~0ull; int bm = 0;
#pragma unroll
      for (int m = 0; m < 8; m++) {
        u64 km = m2[m][h[m]];
        if (km < best) { best = km; bm = m; }
      }
#pragma unroll
      for (int m = 0; m < 8; m++) h[m] += (bm == m);
    }
    ws[WS_TAU + q] = keyhi_f((unsigned)(best >> 32)) + SLACK;
    ((unsigned*)(ws + WS_CNT))[q] = 0u;
  }
}

/* ---------------- K3: candidate gather + exact fp32 refine + mode ------ */
__global__ __launch_bounds__(256) void knn_final(
    const int* __restrict__ targets, const float* __restrict__ Xm,
    const float* __restrict__ dat, float* __restrict__ ws,
    float* __restrict__ out) {
  const int q = blockIdx.x;
  const int t = threadIdx.x;
  const int lane = t & 63, wave = t >> 6;
  __shared__ float qrow[DD];
  __shared__ unsigned lst[LCAP];
  __shared__ int nlist;
  __shared__ u64 wk4[4][KNN];
  if (t == 0) nlist = 0;
  if (t < 128) ((float4*)qrow)[t] = ((const float4*)(Xm + (size_t)q * DD))[t];
  __syncthreads();
  const float tr = ws[WS_TAU + q];
  const u64* samp = ((const u64*)(ws + WS_CKS)) + (size_t)q * NSAMP * KNN;
  for (int j = t; j < NSAMP * KNN; j += 256) {
    u64 k = samp[j];
    if (keyhi_f((unsigned)(k >> 32)) < tr) {
      int s_ = atomicAdd(&nlist, 1);
      if (s_ < LCAP) lst[s_] = (unsigned)k;
    }
  }
  unsigned c = ((const unsigned*)(ws + WS_CNT))[q];
  if (c > CAP) c = CAP;
  const u64* buf = ((const u64*)(ws + WS_BUF)) + (size_t)q * CAP;
  for (int j = t; j < (int)c; j += 256) {
    int s_ = atomicAdd(&nlist, 1);
    if (s_ < LCAP) lst[s_] = (unsigned)buf[j];
  }
  __syncthreads();
  const int n = nlist < LCAP ? nlist : LCAP;

  u64 kl[KNN];
#pragma unroll
  for (int u = 0; u < KNN; u++) kl[u] = ~0ull;
  const float4* qv = (const float4*)qrow;
  const float4 q0 = qv[lane * 2], q1 = qv[lane * 2 + 1];
  /* 2-way ILP: two candidates per iteration so the serial shfl-reduce
     chains overlap; early-reject guard before ins10. */
  for (int j = wave; j < n; j += 8) {
    const unsigned i0 = lst[j];
    const int has1 = (j + 4) < n;
    const unsigned i1 = has1 ? lst[j + 4] : i0;
    const float4* x0 = (const float4*)(dat + (size_t)i0 * DD) + lane * 2;
    const float4* x1 = (const float4*)(dat + (size_t)i1 * DD) + lane * 2;
    const float4 a0 = x0[0], a1 = x0[1];
    const float4 b0 = x1[0], b1 = x1[1];
    float p0 = a0.x * q0.x, p1 = b0.x * q0.x;
    p0 = fmaf(a0.y, q0.y, p0); p1 = fmaf(b0.y, q0.y, p1);
    p0 = fmaf(a0.z, q0.z, p0); p1 = fmaf(b0.z, q0.z, p1);
    p0 = fmaf(a0.w, q0.w, p0); p1 = fmaf(b0.w, q0.w, p1);
    p0 = fmaf(a1.x, q1.x, p0); p1 = fmaf(b1.x, q1.x, p1);
    p0 = fmaf(a1.y, q1.y, p0); p1 = fmaf(b1.y, q1.y, p1);
    p0 = fmaf(a1.z, q1.z, p0); p1 = fmaf(b1.z, q1.z, p1);
    p0 = fmaf(a1.w, q1.w, p0); p1 = fmaf(b1.w, q1.w, p1);
#pragma unroll
    for (int s_ = 1; s_ < 64; s_ <<= 1) {
      p0 += __shfl_xor(p0, s_, 64);
      p1 += __shfl_xor(p1, s_, 64);
    }
    float d0 = fmaf(-2.f, p0, ws[WS_D2 + i0]);
    u64 k0 = mkkey(d0, (int)i0);
    if (k0 < kl[KNN - 1]) ins10(kl, k0);
    if (has1) {
      float d1 = fmaf(-2.f, p1, ws[WS_D2 + i1]);
      u64 k1 = mkkey(d1, (int)i1);
      if (k1 < kl[KNN - 1]) ins10(kl, k1);
    }
  }
  if (lane == 0)
#pragma unroll
    for (int u = 0; u < KNN; u++) wk4[wave][u] = kl[u];
  __syncthreads();
  if (t == 0) {
    int h[4] = {0, 0, 0, 0};
    int fi[KNN];
    for (int pick = 0; pick < KNN; pick++) {
      u64 best = ~0ull; int bm = 0;
#pragma unroll
      for (int m = 0; m < 4; m++) {
        u64 km = wk4[m][h[m]];
        if (km < best) { best = km; bm = m; }
      }
      fi[pick] = (int)(unsigned)(best & 0xffffffffu);
      h[bm]++;
    }
    int lab[KNN];
#pragma unroll
    for (int u = 0; u < KNN; u++) lab[u] = targets[fi[u]];
    int bc = 0, bl = INT_MAX;
#pragma unroll
    for (int i = 0; i < KNN; i++) {
      int cc = 0;
#pragma unroll
      for (int j = 0; j < KNN; j++) cc += (lab[j] == lab[i]) ? 1 : 0;
      if (cc > bc || (cc == bc && lab[i] < bl)) { bc = cc; bl = lab[i]; }
    }
    out[q] = (float)bl;
  }
}

extern "C" void kernel_launch(void* const* d_in, const int* in_sizes, int n_in,
                              void* d_out, int out_size, void* d_ws, size_t ws_size,
                              hipStream_t stream) {
  const float* Xm  = (const float*)d_in[0];
  const float* dat = (const float*)d_in[1];
  const int* targets = (const int*)d_in[2];
  float* out = (float*)d_out;
  float* ws  = (float*)d_ws;
  const bool pre = ws_size >= (size_t)WS_END * 4;   /* constant per process */

  hipLaunchKernelGGL(conv_kernel, dim3(NS + QN * DD / 8 / 256), dim3(256), 0,
                     stream, dat, Xm, ws);
  if (pre) {
    hipLaunchKernelGGL((knn_chunk<1, 0>), dim3(QB, NSAMP), dim3(256), 0, stream, dat, ws, 0);
    hipLaunchKernelGGL(tau_kernel, dim3(QN), dim3(64), 0, stream, ws);
    hipLaunchKernelGGL((knn_chunk<1, 1>), dim3(QB, NREST), dim3(256), 0, stream, dat, ws, NSAMP);
  } else {
    hipLaunchKernelGGL((knn_chunk<0, 0>), dim3(QB, NSAMP), dim3(256), 0, stream, dat, ws, 0);
    hipLaunchKernelGGL(tau_kernel, dim3(QN), dim3(64), 0, stream, ws);
    hipLaunchKernelGGL((knn_chunk<0, 1>), dim3(QB, NREST), dim3(256), 0, stream, dat, ws, NSAMP);
  }
  hipLaunchKernelGGL(knn_final, dim3(QN), dim3(256), 0, stream, targets, Xm, dat, ws, out);
}

// Round 10
// 331.917 us; speedup vs baseline: 1.1072x; 1.0099x over previous
//
#include <hip/hip_runtime.h>
#include <math.h>
#include <limits.h>

#define QN 1024
#define NN 50000
#define NPAD 50048        /* 391*128 exactly */
#define DD 512
#define KNN 10
#define NT 128
#define QTB 128
#define BK 32
#define NS 391
#define QB 8
#define NSAMP 63
#define NREST (NS - NSAMP)    /* 328 = 8*41 -> XCD remap stays bijective */
#define CAP 512
#define SLACK 4.0f            /* hi-only d~ error: sigma~0.18 on d^2; 4.0 ~ 22 sigma */
#define LCAP 1152             /* >= NSAMP*KNN + CAP worst case (630+512=1142) */

/* workspace layout, in 4-byte words */
#define WS_D2  0
#define WS_TAU 50048                       /* float[1024] (threshold, slacked) */
#define WS_CNT (WS_TAU + 1024)
#define WS_XH  (WS_CNT + 1024)
#define WS_CKS (WS_XH + QN * DD / 2)       /* u64[QN*NSAMP*KNN] */
#define WS_BUF (WS_CKS + QN * NSAMP * KNN * 2)
#define WS_DH  (WS_BUF + QN * CAP * 2)     /* tiled data hi: 391*16*8192 B */
#define WS_END (WS_DH + NS * 16 * 2048)

typedef __attribute__((ext_vector_type(8))) short short8;
typedef __attribute__((ext_vector_type(4))) float f32x4;
typedef unsigned long long u64;

__device__ __forceinline__ u64 mkkey(float f, int idx) {
  unsigned u = __float_as_uint(f);
  unsigned m = u ^ ((unsigned)((int)u >> 31) | 0x80000000u);
  return ((u64)m << 32) | (unsigned)idx;
}

/* decode the float from the hi-32 of a key */
__device__ __forceinline__ float keyhi_f(unsigned m) {
  unsigned u = (m & 0x80000000u) ? (m ^ 0x80000000u) : ~m;
  return __uint_as_float(u);
}

/* pack bf16(x),bf16(y) (round-to-nearest-even) into one u32 */
__device__ __forceinline__ unsigned cvth(float x, float y) {
  unsigned ux = __float_as_uint(x), uy = __float_as_uint(y);
  unsigned rx = ux + 0x7fffu + ((ux >> 16) & 1u);
  unsigned ry = uy + 0x7fffu + ((uy >> 16) & 1u);
  return (rx >> 16) | (ry & 0xffff0000u);
}

__device__ __forceinline__ void glds16(const void* g, void* l) {
  __builtin_amdgcn_global_load_lds(
      (const __attribute__((address_space(1))) unsigned*)g,
      (__attribute__((address_space(3))) unsigned*)l, 16, 0, 0);
}

__device__ __forceinline__ void ins10(u64* kl, u64 k) {
#pragma unroll
  for (int u = 0; u < KNN; u++) {
    u64 lo = (k < kl[u]) ? k : kl[u];
    u64 hi = (k < kl[u]) ? kl[u] : k;
    kl[u] = lo; k = hi;
  }
}

struct EpiT  { float sq[64][132]; };
struct ListT { u64 kl[64][4][KNN]; };
struct Smem0 {
  union { unsigned char bh[8192]; EpiT e; ListT l; } u;
  float d2loc[128];
};

/* ---- K01 (fused): one grid, three block roles.
   [0, 504):        MODE0 sampled blocks (slices 0..62): self-convert the
                    slice from raw dat (PRE=0-proven pattern), compute
                    slice norms (LDS broadcast + racing-identical global
                    writes for knn_final), GEMM vs raw-converted A, and
                    emit per-slice top-10 samples to CKS. (DH image for
                    these slices is never read -> no mirror writes.)
   [504, 832):      conv of the 328 non-sampled slices (r0-proven code).
   [832, 1088):     X preconvert to the frag-direct hi image (read only
                    by knn_filter, next launch).
   r9 BUG (absmax 99): the MODE0 norm had s += v3.z*v3.w instead of
   v3.z*v3.z, corrupting D2 for rows 0..8063. Fixed here; no other
   change. ---------------------------------------------------------------- */
__global__ __launch_bounds__(256, 3) void fused_kernel(
    const float* __restrict__ dat, const float* __restrict__ Xm,
    float* __restrict__ ws) {
  const int bid = (int)blockIdx.x;
  const int t = threadIdx.x;

  if (bid >= QB * NSAMP + NREST) {
    /* ---- convX: frag-direct hi image. 16B block index
       g = (b*16 + kc)*64 + l; b=row>>4, kc=col/32, l=sub*16+(row&15). */
    const int g = (bid - (QB * NSAMP + NREST)) * 256 + t;   /* 0..65535 */
    const int b = g >> 10, kc = (g >> 6) & 15, l = g & 63;
    const int row = b * 16 + (l & 15);
    const int col = kc * 32 + (l >> 4) * 8;
    const float4* p = (const float4*)(Xm + (size_t)row * DD + col);
    float4 v0 = p[0], v1 = p[1];
    ((uint4*)(ws + WS_XH))[g] = make_uint4(
        cvth(v0.x, v0.y), cvth(v0.z, v0.w), cvth(v1.x, v1.y), cvth(v1.z, v1.w));
    return;
  }

  if (bid >= QB * NSAMP) {
    /* ---- convD for non-sampled slices (r0-proven, slice offset) */
    const int slice = NSAMP + (bid - QB * NSAMP);
    const int row = t >> 1, h2 = t & 1;
    const int gr = slice * NT + row;
    const int r15 = row & 15;
    float s = 0.f;
#pragma unroll
    for (int kc8 = 0; kc8 < 8; kc8++) {
      const int kc = h2 * 8 + kc8;
      float4 v[8];
      if (gr < NN) {
        const float4* src = (const float4*)(dat + (size_t)gr * DD + kc * 32);
#pragma unroll
        for (int j = 0; j < 8; j++) v[j] = src[j];
      } else {
#pragma unroll
        for (int j = 0; j < 8; j++) v[j] = make_float4(0.f, 0.f, 0.f, 0.f);
      }
      unsigned hw[16];
#pragma unroll
      for (int j = 0; j < 8; j++) {
        s = fmaf(v[j].x, v[j].x, s); s = fmaf(v[j].y, v[j].y, s);
        s = fmaf(v[j].z, v[j].z, s); s = fmaf(v[j].w, v[j].w, s);
        hw[2 * j]     = cvth(v[j].x, v[j].y);
        hw[2 * j + 1] = cvth(v[j].z, v[j].w);
      }
      uint4* dhp = (uint4*)((unsigned char*)(ws + WS_DH) +
                            (((size_t)slice * 16 + kc) * 8 + (row >> 4)) * 1024);
#pragma unroll
      for (int qd = 0; qd < 4; qd++)
        dhp[qd * 16 + r15] = make_uint4(hw[4 * qd], hw[4 * qd + 1], hw[4 * qd + 2], hw[4 * qd + 3]);
    }
    s += __shfl_xor(s, 1, 64);
    if (h2 == 0) ws[WS_D2 + gr] = (gr < NN) ? s : __builtin_inff();
    return;
  }

  /* ---- MODE0 sampled block ---- */
  __shared__ __align__(16) Smem0 sm;
  const int m = bid;
  const int bqx = m & 7;          /* query block */
  const int bsy = m >> 3;         /* sampled slice 0..62 */
  const int qbase = bqx * QTB;
  const int slice = bsy;
  const int nbase = slice * NT;
  const int lane = t & 63, wave = t >> 6;
  const int wn = wave & 1, wq = wave >> 1;

  f32x4 acc[4][4];
#pragma unroll
  for (int i = 0; i < 4; i++)
#pragma unroll
    for (int j = 0; j < 4; j++) acc[i][j] = (f32x4)0.f;

  const int brow = t >> 1, bh_half = t & 1;
  const int bgr = nbase + brow;
  const int bpanel = (brow >> 4) * 1024;
  const int bchunk = (brow & 15) * 16;
  float s = 0.f;
  for (int kc = 0; kc < 16; kc++) {
    const int kk = kc * BK;
    /* A-frags raw-converted from X (no image dependency) */
    short8 fah[4];
#pragma unroll
    for (int i = 0; i < 4; i++) {
      const int p = wq * 4 + i;
      const float4* xr = (const float4*)(
          Xm + (size_t)(qbase + p * 16 + (lane & 15)) * DD + kk + (lane >> 4) * 8);
      float4 v0 = xr[0], v1 = xr[1];
      union { unsigned w[4]; short8 s8; } pk;
      pk.w[0] = cvth(v0.x, v0.y); pk.w[1] = cvth(v0.z, v0.w);
      pk.w[2] = cvth(v1.x, v1.y); pk.w[3] = cvth(v1.z, v1.w);
      fah[i] = pk.s8;
    }
    __syncthreads();
    {
      float4 v0 = make_float4(0.f, 0.f, 0.f, 0.f), v1 = v0, v2 = v0, v3 = v0;
      if (bgr < NN) {
        const float4* src = (const float4*)(dat + (size_t)bgr * DD + kk + bh_half * 16);
        v0 = src[0]; v1 = src[1]; v2 = src[2]; v3 = src[3];
      }
      s = fmaf(v0.x, v0.x, s); s = fmaf(v0.y, v0.y, s);
      s = fmaf(v0.z, v0.z, s); s = fmaf(v0.w, v0.w, s);
      s = fmaf(v1.x, v1.x, s); s = fmaf(v1.y, v1.y, s);
      s = fmaf(v1.z, v1.z, s); s = fmaf(v1.w, v1.w, s);
      s = fmaf(v2.x, v2.x, s); s = fmaf(v2.y, v2.y, s);
      s = fmaf(v2.z, v2.z, s); s = fmaf(v2.w, v2.w, s);
      s = fmaf(v3.x, v3.x, s); s = fmaf(v3.y, v3.y, s);
      s = fmaf(v3.z, v3.z, s); s = fmaf(v3.w, v3.w, s);   /* r9 bug fixed */
      uint4 q0 = make_uint4(cvth(v0.x, v0.y), cvth(v0.z, v0.w), cvth(v1.x, v1.y), cvth(v1.z, v1.w));
      uint4 q1 = make_uint4(cvth(v2.x, v2.y), cvth(v2.z, v2.w), cvth(v3.x, v3.y), cvth(v3.z, v3.w));
      unsigned char* bhp = sm.u.bh + bpanel;
      *(uint4*)(bhp + (2 * bh_half) * 256 + bchunk)     = q0;
      *(uint4*)(bhp + (2 * bh_half + 1) * 256 + bchunk) = q1;
    }
    __syncthreads();
    const int fragoff = lane * 16;
    short8 fbh[4];
#pragma unroll
    for (int i = 0; i < 4; i++)
      fbh[i] = *(const short8*)(sm.u.bh + (wn * 4 + i) * 1024 + fragoff);
    __syncthreads();
#pragma unroll
    for (int mt = 0; mt < 4; mt++)
#pragma unroll
      for (int nt = 0; nt < 4; nt++)
        acc[mt][nt] = __builtin_amdgcn_mfma_f32_16x16x32_bf16(fah[mt], fbh[nt], acc[mt][nt], 0, 0, 0);
  }
  /* slice row norms: halves -> full row via shfl; LDS broadcast for the
     epilogue + global write for knn_final (all bqx write identical
     values -> benign race) */
  s += __shfl_xor(s, 1, 64);
  if (bh_half == 0) {
    sm.d2loc[brow] = s;
    ws[WS_D2 + bgr] = s;
  }

  /* ---- sampled epilogue: per-slice top-10 of d~ -> CKS ---- */
#pragma unroll
  for (int pass = 0; pass < 2; pass++) {
    __syncthreads();
    if (wq == pass) {
#pragma unroll
      for (int nt = 0; nt < 4; nt++) {
        int col = wn * 64 + nt * 16 + (lane & 15);
        float d2v = sm.d2loc[col];
#pragma unroll
        for (int mt = 0; mt < 4; mt++)
#pragma unroll
          for (int rg = 0; rg < 4; rg++) {
            int lr = mt * 16 + (lane >> 4) * 4 + rg;
            sm.u.e.sq[lr][col] = fmaf(-2.f, acc[mt][nt][rg], d2v);
          }
      }
    }
    __syncthreads();
    {
      const int r = t >> 2, s4 = t & 3;
      u64 kl[KNN];
#pragma unroll
      for (int u = 0; u < KNN; u++) kl[u] = ~0ull;
      for (int jj = 0; jj < 32; jj++) {
        int c = s4 * 32 + ((jj + r + 8 * s4) & 31);
        float v = sm.u.e.sq[r][c];
        ins10(kl, mkkey(v, nbase + c));
      }
      __syncthreads();
#pragma unroll
      for (int u = 0; u < KNN; u++) sm.u.l.kl[r][s4][u] = kl[u];
    }
    __syncthreads();
    if (t < 64) {
      u64* dst = ((u64*)(ws + WS_CKS)) +
                 ((size_t)(qbase + pass * 64 + t) * NSAMP + bsy) * KNN;
      int h0 = 0, h1 = 0, h2c = 0, h3 = 0;
      for (int pick = 0; pick < KNN; pick++) {
        u64 k0 = sm.u.l.kl[t][0][h0], k1 = sm.u.l.kl[t][1][h1];
        u64 k2 = sm.u.l.kl[t][2][h2c], k3 = sm.u.l.kl[t][3][h3];
        u64 best = k0; int bm = 0;
        if (k1 < best) { best = k1; bm = 1; }
        if (k2 < best) { best = k2; bm = 2; }
        if (k3 < best) { best = k3; bm = 3; }
        dst[pick] = best;
        h0 += (bm == 0); h1 += (bm == 1); h2c += (bm == 2); h3 += (bm == 3);
      }
    }
  }
}

/* ------- K2: filter GEMM (r5-proven loop, verbatim): A frag-direct from
   the X image (plain loads, overlap the barrier), B staged hi-only via
   global_load_lds, two barriers per kc. 0.223 us/slice-8qb measured. --- */
struct SmemF { unsigned char bh[8192]; float tau[128]; };

__global__ __launch_bounds__(256, 3) void knn_filter(
    float* __restrict__ ws) {
  __shared__ __align__(16) SmemF sm;
  /* XCD-aware remap: cluster a slice's 8 qblocks onto one XCD
     (r3-verified: FETCH 374->58 MB). gridDim.y = 328, % 8 == 0. */
  const int n = (int)(blockIdx.y * gridDim.x + blockIdx.x);
  const int mm = n >> 3;
  const int ypx = (int)(gridDim.y >> 3);
  const int bqx = mm & 7;
  const int bsy = (n & 7) * ypx + (mm >> 3);
  const int qbase = bqx * QTB;
  const int slice = bsy + NSAMP;
  const int nbase = slice * NT;
  const int t = threadIdx.x;
  const int lane = t & 63, wave = t >> 6;
  const int wn = wave & 1, wq = wave >> 1;
  const unsigned char* dh = (const unsigned char*)(ws + WS_DH);
  const char* xfh = (const char*)(ws + WS_XH);
  /* A-frag byte base: block ((bqx*8 + wq*4 + i)*16 + kc)*64 + lane */
  const int abase = (((bqx * 8 + wq * 4) * 16) * 64 + lane) * 16;

  f32x4 acc[4][4];
#pragma unroll
  for (int i = 0; i < 4; i++)
#pragma unroll
    for (int j = 0; j < 4; j++) acc[i][j] = (f32x4)0.f;

  auto stageB = [&](int kc) {
#pragma unroll
    for (int i = 0; i < 2; i++) {
      int p = wave * 2 + i;
      const unsigned char* g = dh +
          (((size_t)slice * 16 + kc) * 8 + p) * 1024 + lane * 16;
      glds16(g, sm.bh + p * 1024);
    }
  };

  stageB(0);
  for (int kc = 0; kc < 16; kc++) {
    short8 fah[4];
#pragma unroll
    for (int i = 0; i < 4; i++)
      fah[i] = *(const short8*)(xfh + abase + i * 16384 + kc * 1024);
    __syncthreads();                    /* DMA(kc) complete */
    const int fragoff = lane * 16;
    short8 fbh[4];
#pragma unroll
    for (int i = 0; i < 4; i++)
      fbh[i] = *(const short8*)(sm.bh + (wn * 4 + i) * 1024 + fragoff);
    __syncthreads();                    /* all waves done reading LDS */
    if (kc < 15) stageB(kc + 1);        /* overlaps the MFMAs below */
#pragma unroll
    for (int mt = 0; mt < 4; mt++)
#pragma unroll
      for (int nt = 0; nt < 4; nt++)
        acc[mt][nt] = __builtin_amdgcn_mfma_f32_16x16x32_bf16(fah[mt], fbh[nt], acc[mt][nt], 0, 0, 0);
  }

  /* threshold filter: float compare against slacked tau */
  if (t < 128) sm.tau[t] = ws[WS_TAU + qbase + t];
  __syncthreads();
  unsigned* cnt = (unsigned*)(ws + WS_CNT);
  u64* buf = (u64*)(ws + WS_BUF);
  float d2v[4];
#pragma unroll
  for (int nt = 0; nt < 4; nt++)
    d2v[nt] = ws[WS_D2 + nbase + wn * 64 + nt * 16 + (lane & 15)];
#pragma unroll
  for (int mt = 0; mt < 4; mt++)
#pragma unroll
    for (int rg = 0; rg < 4; rg++) {
      int row = wq * 64 + mt * 16 + (lane >> 4) * 4 + rg;
      float tr = sm.tau[row];
#pragma unroll
      for (int nt = 0; nt < 4; nt++) {
        float d = fmaf(-2.f, acc[mt][nt][rg], d2v[nt]);
        if (d < tr) {
          int col = nbase + wn * 64 + nt * 16 + (lane & 15);
          int q = qbase + row;
          unsigned slot = atomicAdd(cnt + q, 1u);
          if (slot < CAP) buf[(size_t)q * CAP + slot] = mkkey(d, col);
        }
      }
    }
}

/* ---------------- K2t: per-query tau = 10th of sampled keys + SLACK ---- */
__global__ __launch_bounds__(64) void tau_kernel(float* __restrict__ ws) {
  const int q = blockIdx.x;
  const int t = threadIdx.x;
  const u64* samp = ((const u64*)(ws + WS_CKS)) + (size_t)q * NSAMP * KNN;
  const int NC = NSAMP * KNN;
  u64 kl[KNN];
#pragma unroll
  for (int u = 0; u < KNN; u++) kl[u] = ~0ull;
  for (int j = t; j < NC; j += 64) ins10(kl, samp[j]);
  __shared__ u64 wk[64][KNN];
  __shared__ u64 m2[8][KNN];
#pragma unroll
  for (int u = 0; u < KNN; u++) wk[t][u] = kl[u];
  __syncthreads();
  if (t < 8) {
    int h[8] = {0, 0, 0, 0, 0, 0, 0, 0};
    for (int pick = 0; pick < KNN; pick++) {
      u64 best = ~0ull; int bm = 0;
#pragma unroll
      for (int m = 0; m < 8; m++) {
        u64 km = wk[t * 8 + m][h[m]];
        if (km < best) { best = km; bm = m; }
      }
      m2[t][pick] = best;
#pragma unroll
      for (int m = 0; m < 8; m++) h[m] += (bm == m);
    }
  }
  __syncthreads();
  if (t == 0) {
    int h[8] = {0, 0, 0, 0, 0, 0, 0, 0};
    u64 best = 0;
    for (int pick = 0; pick < KNN; pick++) {
      best = ~0ull; int bm = 0;
#pragma unroll
      for (int m = 0; m < 8; m++) {
        u64 km = m2[m][h[m]];
        if (km < best) { best = km; bm = m; }
      }
#pragma unroll
      for (int m = 0; m < 8; m++) h[m] += (bm == m);
    }
    ws[WS_TAU + q] = keyhi_f((unsigned)(best >> 32)) + SLACK;
    ((unsigned*)(ws + WS_CNT))[q] = 0u;
  }
}

/* ---------------- K3: candidate gather + exact fp32 refine + mode ------ */
__global__ __launch_bounds__(256) void knn_final(
    const int* __restrict__ targets, const float* __restrict__ Xm,
    const float* __restrict__ dat, float* __restrict__ ws,
    float* __restrict__ out) {
  const int q = blockIdx.x;
  const int t = threadIdx.x;
  const int lane = t & 63, wave = t >> 6;
  __shared__ float qrow[DD];
  __shared__ unsigned lst[LCAP];
  __shared__ int nlist;
  __shared__ u64 wk4[4][KNN];
  if (t == 0) nlist = 0;
  if (t < 128) ((float4*)qrow)[t] = ((const float4*)(Xm + (size_t)q * DD))[t];
  __syncthreads();
  const float tr = ws[WS_TAU + q];
  const u64* samp = ((const u64*)(ws + WS_CKS)) + (size_t)q * NSAMP * KNN;
  for (int j = t; j < NSAMP * KNN; j += 256) {
    u64 k = samp[j];
    if (keyhi_f((unsigned)(k >> 32)) < tr) {
      int s_ = atomicAdd(&nlist, 1);
      if (s_ < LCAP) lst[s_] = (unsigned)k;
    }
  }
  unsigned c = ((const unsigned*)(ws + WS_CNT))[q];
  if (c > CAP) c = CAP;
  const u64* buf = ((const u64*)(ws + WS_BUF)) + (size_t)q * CAP;
  for (int j = t; j < (int)c; j += 256) {
    int s_ = atomicAdd(&nlist, 1);
    if (s_ < LCAP) lst[s_] = (unsigned)buf[j];
  }
  __syncthreads();
  const int n = nlist < LCAP ? nlist : LCAP;

  u64 kl[KNN];
#pragma unroll
  for (int u = 0; u < KNN; u++) kl[u] = ~0ull;
  const float4* qv = (const float4*)qrow;
  const float4 q0 = qv[lane * 2], q1 = qv[lane * 2 + 1];
  /* 2-way ILP: two candidates per iteration so the serial shfl-reduce
     chains overlap; early-reject guard before ins10. */
  for (int j = wave; j < n; j += 8) {
    const unsigned i0 = lst[j];
    const int has1 = (j + 4) < n;
    const unsigned i1 = has1 ? lst[j + 4] : i0;
    const float4* x0 = (const float4*)(dat + (size_t)i0 * DD) + lane * 2;
    const float4* x1 = (const float4*)(dat + (size_t)i1 * DD) + lane * 2;
    const float4 a0 = x0[0], a1 = x0[1];
    const float4 b0 = x1[0], b1 = x1[1];
    float p0 = a0.x * q0.x, p1 = b0.x * q0.x;
    p0 = fmaf(a0.y, q0.y, p0); p1 = fmaf(b0.y, q0.y, p1);
    p0 = fmaf(a0.z, q0.z, p0); p1 = fmaf(b0.z, q0.z, p1);
    p0 = fmaf(a0.w, q0.w, p0); p1 = fmaf(b0.w, q0.w, p1);
    p0 = fmaf(a1.x, q1.x, p0); p1 = fmaf(b1.x, q1.x, p1);
    p0 = fmaf(a1.y, q1.y, p0); p1 = fmaf(b1.y, q1.y, p1);
    p0 = fmaf(a1.z, q1.z, p0); p1 = fmaf(b1.z, q1.z, p1);
    p0 = fmaf(a1.w, q1.w, p0); p1 = fmaf(b1.w, q1.w, p1);
#pragma unroll
    for (int s_ = 1; s_ < 64; s_ <<= 1) {
      p0 += __shfl_xor(p0, s_, 64);
      p1 += __shfl_xor(p1, s_, 64);
    }
    float d0 = fmaf(-2.f, p0, ws[WS_D2 + i0]);
    u64 k0 = mkkey(d0, (int)i0);
    if (k0 < kl[KNN - 1]) ins10(kl, k0);
    if (has1) {
      float d1 = fmaf(-2.f, p1, ws[WS_D2 + i1]);
      u64 k1 = mkkey(d1, (int)i1);
      if (k1 < kl[KNN - 1]) ins10(kl, k1);
    }
  }
  if (lane == 0)
#pragma unroll
    for (int u = 0; u < KNN; u++) wk4[wave][u] = kl[u];
  __syncthreads();
  if (t == 0) {
    int h[4] = {0, 0, 0, 0};
    int fi[KNN];
    for (int pick = 0; pick < KNN; pick++) {
      u64 best = ~0ull; int bm = 0;
#pragma unroll
      for (int m = 0; m < 4; m++) {
        u64 km = wk4[m][h[m]];
        if (km < best) { best = km; bm = m; }
      }
      fi[pick] = (int)(unsigned)(best & 0xffffffffu);
      h[bm]++;
    }
    int lab[KNN];
#pragma unroll
    for (int u = 0; u < KNN; u++) lab[u] = targets[fi[u]];
    int bc = 0, bl = INT_MAX;
#pragma unroll
    for (int i = 0; i < KNN; i++) {
      int cc = 0;
#pragma unroll
      for (int j = 0; j < KNN; j++) cc += (lab[j] == lab[i]) ? 1 : 0;
      if (cc > bc || (cc == bc && lab[i] < bl)) { bc = cc; bl = lab[i]; }
    }
    out[q] = (float)bl;
  }
}

extern "C" void kernel_launch(void* const* d_in, const int* in_sizes, int n_in,
                              void* d_out, int out_size, void* d_ws, size_t ws_size,
                              hipStream_t stream) {
  const float* Xm  = (const float*)d_in[0];
  const float* dat = (const float*)d_in[1];
  const int* targets = (const int*)d_in[2];
  float* out = (float*)d_out;
  float* ws  = (float*)d_ws;

  hipLaunchKernelGGL(fused_kernel, dim3(QB * NSAMP + NREST + 256), dim3(256), 0,
                     stream, dat, Xm, ws);
  hipLaunchKernelGGL(tau_kernel, dim3(QN), dim3(64), 0, stream, ws);
  hipLaunchKernelGGL(knn_filter, dim3(QB, NREST), dim3(256), 0, stream, ws);
  hipLaunchKernelGGL(knn_final, dim3(QN), dim3(256), 0, stream, targets, Xm, dat, ws, out);
}